// Round 1
// baseline (1418.062 us; speedup 1.0000x reference)
//
#include <hip/hip_runtime.h>
#include <hip/hip_bf16.h>

typedef __attribute__((ext_vector_type(8))) __bf16 bf16x8;
typedef __attribute__((ext_vector_type(4))) float f32x4;

#define F_DIM 512
#define D_DIM 128

__device__ __forceinline__ unsigned short f32_to_bf16_rn(float x) {
    union { float f; unsigned u; } v; v.f = x;
    unsigned u = v.u;
    unsigned rounded = u + 0x7fffu + ((u >> 16) & 1u);
    return (unsigned short)(rounded >> 16);
}

// W [512][128] f32 -> Wt [128][512] bf16 (transposed, k-contiguous for B frags)
__global__ void wt_kernel(const float* __restrict__ W, unsigned short* __restrict__ Wt) {
    int idx = blockIdx.x * blockDim.x + threadIdx.x;   // 65536 total
    int n = idx >> 9;        // 0..127
    int k = idx & 511;       // 0..511
    Wt[idx] = f32_to_bf16_rn(W[k * D_DIM + n]);
}

// support = relu(feature @ W), bf16 MFMA 16x16x32, block tile 128(M) x 128(N)
__global__ __launch_bounds__(256) void gemm_relu_kernel(
    const float* __restrict__ A,            // feature [N][512] f32
    const unsigned short* __restrict__ Bt,  // Wt [128][512] bf16
    float* __restrict__ S,                  // support [N][128] f32
    int Nrows)
{
    __shared__ unsigned short Al[128 * 40];  // [m][k] bf16, padded stride 40
    __shared__ unsigned short Bl[128 * 40];  // [n][k] bf16, padded stride 40

    const int tid  = threadIdx.x;
    const int wave = tid >> 6;
    const int lane = tid & 63;
    const int m0   = blockIdx.x * 128;
    const int g    = lane >> 4;     // k-group 0..3
    const int r16  = lane & 15;

    f32x4 acc[2][8];
#pragma unroll
    for (int i = 0; i < 2; ++i)
#pragma unroll
        for (int j = 0; j < 8; ++j) acc[i][j] = (f32x4)0.0f;

    for (int ks = 0; ks < 16; ++ks) {
        // stage A: 128 rows x 32 k, f32 -> bf16
#pragma unroll
        for (int it = 0; it < 4; ++it) {
            int idx = tid + it * 256;          // 0..1023
            int r   = idx >> 3;                // row 0..127
            int c4  = idx & 7;                 // float4 chunk 0..7
            int grow = m0 + r;
            float4 v = make_float4(0.f, 0.f, 0.f, 0.f);
            if (grow < Nrows) v = *(const float4*)&A[(size_t)grow * F_DIM + ks * 32 + c4 * 4];
            unsigned p0 = ((unsigned)f32_to_bf16_rn(v.y) << 16) | f32_to_bf16_rn(v.x);
            unsigned p1 = ((unsigned)f32_to_bf16_rn(v.w) << 16) | f32_to_bf16_rn(v.z);
            uint2 pk; pk.x = p0; pk.y = p1;
            *(uint2*)&Al[r * 40 + c4 * 4] = pk;
        }
        // stage B: 128 n-rows x 32 k bf16 (already bf16 in Wt)
#pragma unroll
        for (int it = 0; it < 2; ++it) {
            int idx = tid + it * 256;          // 0..511
            int n   = idx >> 2;                // 0..127
            int koff = (idx & 3) * 8;
            *(uint4*)&Bl[n * 40 + koff] = *(const uint4*)&Bt[n * F_DIM + ks * 32 + koff];
        }
        __syncthreads();

        bf16x8 afrag[2];
#pragma unroll
        for (int mf = 0; mf < 2; ++mf) {
            int row = wave * 32 + mf * 16 + r16;
            afrag[mf] = *(const bf16x8*)&Al[row * 40 + g * 8];
        }
#pragma unroll
        for (int nf = 0; nf < 8; ++nf) {
            bf16x8 bfrag = *(const bf16x8*)&Bl[(nf * 16 + r16) * 40 + g * 8];
#pragma unroll
            for (int mf = 0; mf < 2; ++mf) {
                acc[mf][nf] = __builtin_amdgcn_mfma_f32_16x16x32_bf16(afrag[mf], bfrag, acc[mf][nf], 0, 0, 0);
            }
        }
        __syncthreads();
    }

    // epilogue: relu + store
#pragma unroll
    for (int mf = 0; mf < 2; ++mf) {
#pragma unroll
        for (int nf = 0; nf < 8; ++nf) {
#pragma unroll
            for (int r = 0; r < 4; ++r) {
                int row = m0 + wave * 32 + mf * 16 + g * 4 + r;
                if (row < Nrows) {
                    int col = nf * 16 + r16;
                    float v = acc[mf][nf][r];
                    S[(size_t)row * D_DIM + col] = v > 0.f ? v : 0.f;
                }
            }
        }
    }
}

// out = support + bias  (vectorized float4; 128 cols = 32 float4 per row)
__global__ void init_out_kernel(const float* __restrict__ S, const float* __restrict__ bias,
                                float* __restrict__ out, int total4) {
    int idx = blockIdx.x * blockDim.x + threadIdx.x;
    if (idx >= total4) return;
    float4 s = ((const float4*)S)[idx];
    float4 b = ((const float4*)bias)[idx & 31];
    float4 o;
    o.x = s.x + b.x; o.y = s.y + b.y; o.z = s.z + b.z; o.w = s.w + b.w;
    ((float4*)out)[idx] = o;
}

// per edge: out[row] += val * support[col]; 4 edges/block, 64 lanes x 2 floats
__global__ __launch_bounds__(256) void scatter_kernel(
    const int* __restrict__ ei, const float* __restrict__ ev,
    const float* __restrict__ S, float* __restrict__ out, int E)
{
    int t = blockIdx.x * 256 + threadIdx.x;
    int e = t >> 6;
    if (e >= E) return;
    int lane = t & 63;
    int row = ei[e];
    int col = ei[E + e];
    float val = ev[e];
    float2 s = *(const float2*)&S[(size_t)col * D_DIM + lane * 2];
    float* o = &out[(size_t)row * D_DIM + lane * 2];
    atomicAdd(o,     val * s.x);
    atomicAdd(o + 1, val * s.y);
}

extern "C" void kernel_launch(void* const* d_in, const int* in_sizes, int n_in,
                              void* d_out, int out_size, void* d_ws, size_t ws_size,
                              hipStream_t stream) {
    const float* feature = (const float*)d_in[0];
    const float* W       = (const float*)d_in[1];
    const float* bias    = (const float*)d_in[2];
    const float* ev      = (const float*)d_in[3];
    const int*   ei      = (const int*)d_in[4];
    float* out = (float*)d_out;

    const int N = in_sizes[0] / F_DIM;   // 100000
    const int E = in_sizes[3];           // 1600000

    // workspace layout: support f32 [N*128], then Wt bf16 [128*512]
    float* S = (float*)d_ws;
    unsigned short* Wt = (unsigned short*)(S + (size_t)N * D_DIM);

    wt_kernel<<<(F_DIM * D_DIM) / 256, 256, 0, stream>>>(W, Wt);
    gemm_relu_kernel<<<(N + 127) / 128, 256, 0, stream>>>(feature, Wt, S, N);
    init_out_kernel<<<((N * D_DIM / 4) + 255) / 256, 256, 0, stream>>>(S, bias, out, N * D_DIM / 4);
    scatter_kernel<<<(E + 3) / 4, 256, 0, stream>>>(ei, ev, S, out, E);
}

// Round 2
// 432.876 us; speedup vs baseline: 3.2759x; 3.2759x over previous
//
#include <hip/hip_runtime.h>
#include <hip/hip_bf16.h>

typedef __attribute__((ext_vector_type(8))) __bf16 bf16x8;
typedef __attribute__((ext_vector_type(4))) float f32x4;

#define F_DIM 512
#define D_DIM 128
#define SCAN_CHUNK 2048   // 256 threads x 8 elems

__device__ __forceinline__ unsigned short f32_to_bf16_rn(float x) {
    union { float f; unsigned u; } v; v.f = x;
    unsigned u = v.u;
    unsigned rounded = u + 0x7fffu + ((u >> 16) & 1u);
    return (unsigned short)(rounded >> 16);
}

// W [512][128] f32 -> Wt [128][512] bf16 (transposed, k-contiguous)
__global__ void wt_kernel(const float* __restrict__ W, unsigned short* __restrict__ Wt) {
    int idx = blockIdx.x * blockDim.x + threadIdx.x;   // 65536 total
    int n = idx >> 9;
    int k = idx & 511;
    Wt[idx] = f32_to_bf16_rn(W[k * D_DIM + n]);
}

// support = relu(feature @ W), bf16 MFMA 16x16x32, block tile 128(M) x 128(N)
__global__ __launch_bounds__(256) void gemm_relu_kernel(
    const float* __restrict__ A,
    const unsigned short* __restrict__ Bt,
    float* __restrict__ S,
    int Nrows)
{
    __shared__ unsigned short Al[128 * 40];
    __shared__ unsigned short Bl[128 * 40];

    const int tid  = threadIdx.x;
    const int wave = tid >> 6;
    const int lane = tid & 63;
    const int m0   = blockIdx.x * 128;
    const int g    = lane >> 4;
    const int r16  = lane & 15;

    f32x4 acc[2][8];
#pragma unroll
    for (int i = 0; i < 2; ++i)
#pragma unroll
        for (int j = 0; j < 8; ++j) acc[i][j] = (f32x4)0.0f;

    for (int ks = 0; ks < 16; ++ks) {
#pragma unroll
        for (int it = 0; it < 4; ++it) {
            int idx = tid + it * 256;
            int r   = idx >> 3;
            int c4  = idx & 7;
            int grow = m0 + r;
            float4 v = make_float4(0.f, 0.f, 0.f, 0.f);
            if (grow < Nrows) v = *(const float4*)&A[(size_t)grow * F_DIM + ks * 32 + c4 * 4];
            unsigned p0 = ((unsigned)f32_to_bf16_rn(v.y) << 16) | f32_to_bf16_rn(v.x);
            unsigned p1 = ((unsigned)f32_to_bf16_rn(v.w) << 16) | f32_to_bf16_rn(v.z);
            uint2 pk; pk.x = p0; pk.y = p1;
            *(uint2*)&Al[r * 40 + c4 * 4] = pk;
        }
#pragma unroll
        for (int it = 0; it < 2; ++it) {
            int idx = tid + it * 256;
            int n   = idx >> 2;
            int koff = (idx & 3) * 8;
            *(uint4*)&Bl[n * 40 + koff] = *(const uint4*)&Bt[n * F_DIM + ks * 32 + koff];
        }
        __syncthreads();

        bf16x8 afrag[2];
#pragma unroll
        for (int mf = 0; mf < 2; ++mf) {
            int row = wave * 32 + mf * 16 + r16;
            afrag[mf] = *(const bf16x8*)&Al[row * 40 + g * 8];
        }
#pragma unroll
        for (int nf = 0; nf < 8; ++nf) {
            bf16x8 bfrag = *(const bf16x8*)&Bl[(nf * 16 + r16) * 40 + g * 8];
#pragma unroll
            for (int mf = 0; mf < 2; ++mf) {
                acc[mf][nf] = __builtin_amdgcn_mfma_f32_16x16x32_bf16(afrag[mf], bfrag, acc[mf][nf], 0, 0, 0);
            }
        }
        __syncthreads();
    }

#pragma unroll
    for (int mf = 0; mf < 2; ++mf) {
#pragma unroll
        for (int nf = 0; nf < 8; ++nf) {
#pragma unroll
            for (int r = 0; r < 4; ++r) {
                int row = m0 + wave * 32 + mf * 16 + g * 4 + r;
                if (row < Nrows) {
                    int col = nf * 16 + r16;
                    float v = acc[mf][nf][r];
                    S[(size_t)row * D_DIM + col] = v > 0.f ? v : 0.f;
                }
            }
        }
    }
}

// ---- CSR build ----

__global__ void hist_kernel(const int* __restrict__ ei, int* __restrict__ counts, int E) {
    int e = blockIdx.x * blockDim.x + threadIdx.x;
    if (e < E) atomicAdd(&counts[ei[e]], 1);
}

// per-chunk exclusive scan (256 threads x 8 elems), block sums out
__global__ __launch_bounds__(256) void scan1_kernel(const int* __restrict__ counts,
                                                    int* __restrict__ offsets,
                                                    int* __restrict__ bsum, int n) {
    __shared__ int tsum[256];
    int base = blockIdx.x * SCAN_CHUNK;
    int t = threadIdx.x;
    int local[8];
    int s = 0;
#pragma unroll
    for (int j = 0; j < 8; ++j) {
        int idx = base + t * 8 + j;
        int c = (idx < n) ? counts[idx] : 0;
        local[j] = s;
        s += c;
    }
    tsum[t] = s;
    __syncthreads();
    for (int d = 1; d < 256; d <<= 1) {
        int v = (t >= d) ? tsum[t - d] : 0;
        __syncthreads();
        if (t >= d) tsum[t] += v;
        __syncthreads();
    }
    int texcl = (t > 0) ? tsum[t - 1] : 0;
#pragma unroll
    for (int j = 0; j < 8; ++j) {
        int idx = base + t * 8 + j;
        if (idx < n) offsets[idx] = texcl + local[j];
    }
    if (t == 255) bsum[blockIdx.x] = tsum[255];
}

__global__ void scan2_kernel(const int* __restrict__ bsum, int* __restrict__ bscan, int nb) {
    if (threadIdx.x == 0 && blockIdx.x == 0) {
        int s = 0;
        for (int i = 0; i < nb; ++i) { bscan[i] = s; s += bsum[i]; }
    }
}

__global__ void scan3_kernel(int* __restrict__ offsets, const int* __restrict__ bscan,
                             int n, int Etot) {
    int i = blockIdx.x * blockDim.x + threadIdx.x;
    if (i < n) offsets[i] += bscan[i / SCAN_CHUNK];
    else if (i == n) offsets[n] = Etot;
}

// scatter edges into CSR order: ecv[p] = {col, val}
__global__ void reorder_kernel(const int* __restrict__ ei, const float* __restrict__ ev,
                               int* __restrict__ cursor, uint2* __restrict__ ecv, int E) {
    int e = blockIdx.x * blockDim.x + threadIdx.x;
    if (e >= E) return;
    int r = ei[e];
    int p = atomicAdd(&cursor[r], 1);
    uint2 cv;
    cv.x = (unsigned)ei[E + e];
    cv.y = __float_as_uint(ev[e]);
    ecv[p] = cv;
}

// one wave per row: acc = sum(val * S[col]); out = acc + S[row] + bias
__global__ __launch_bounds__(256) void accum_kernel(
    const uint2* __restrict__ ecv, const int* __restrict__ offsets,
    const float* __restrict__ S, const float* __restrict__ bias,
    float* __restrict__ out, int n)
{
    int wid = (blockIdx.x * 256 + threadIdx.x) >> 6;
    if (wid >= n) return;
    int lane = threadIdx.x & 63;

    int start = offsets[wid];
    int end   = offsets[wid + 1];

    float ax = 0.f, ay = 0.f;
    int i = start;
    for (; i + 1 < end; i += 2) {
        uint2 cv0 = ecv[i];
        uint2 cv1 = ecv[i + 1];
        float2 s0 = *(const float2*)&S[(size_t)cv0.x * D_DIM + lane * 2];
        float2 s1 = *(const float2*)&S[(size_t)cv1.x * D_DIM + lane * 2];
        float v0 = __uint_as_float(cv0.y);
        float v1 = __uint_as_float(cv1.y);
        ax += v0 * s0.x + v1 * s1.x;
        ay += v0 * s0.y + v1 * s1.y;
    }
    if (i < end) {
        uint2 cv = ecv[i];
        float2 s = *(const float2*)&S[(size_t)cv.x * D_DIM + lane * 2];
        float v = __uint_as_float(cv.y);
        ax += v * s.x;
        ay += v * s.y;
    }

    float2 own = *(const float2*)&S[(size_t)wid * D_DIM + lane * 2];
    float2 b   = *(const float2*)&bias[lane * 2];
    float2 o;
    o.x = ax + own.x + b.x;
    o.y = ay + own.y + b.y;
    *(float2*)&out[(size_t)wid * D_DIM + lane * 2] = o;
}

extern "C" void kernel_launch(void* const* d_in, const int* in_sizes, int n_in,
                              void* d_out, int out_size, void* d_ws, size_t ws_size,
                              hipStream_t stream) {
    const float* feature = (const float*)d_in[0];
    const float* W       = (const float*)d_in[1];
    const float* bias    = (const float*)d_in[2];
    const float* ev      = (const float*)d_in[3];
    const int*   ei      = (const int*)d_in[4];
    float* out = (float*)d_out;

    const int N = in_sizes[0] / F_DIM;   // 100000
    const int E = in_sizes[3];           // 1600000
    const int NB = (N + SCAN_CHUNK - 1) / SCAN_CHUNK;

    // workspace layout (256B aligned slabs)
    char* ws = (char*)d_ws;
    size_t cur = 0;
    auto alloc = [&](size_t bytes) -> void* {
        void* p = ws + cur;
        cur = (cur + bytes + 255) & ~(size_t)255;
        return p;
    };
    float*          S       = (float*)alloc((size_t)N * D_DIM * 4);
    unsigned short* Wt      = (unsigned short*)alloc((size_t)D_DIM * F_DIM * 2);
    int*            counts  = (int*)alloc((size_t)N * 4);
    int*            offsets = (int*)alloc((size_t)(N + 1) * 4);
    int*            bsum    = (int*)alloc((size_t)NB * 4);
    int*            bscan   = (int*)alloc((size_t)NB * 4);
    int*            cursor  = (int*)alloc((size_t)N * 4);
    uint2*          ecv     = (uint2*)alloc((size_t)E * 8);
    (void)ws_size;

    // GEMM path
    wt_kernel<<<(F_DIM * D_DIM) / 256, 256, 0, stream>>>(W, Wt);
    gemm_relu_kernel<<<(N + 127) / 128, 256, 0, stream>>>(feature, Wt, S, N);

    // CSR build
    hipMemsetAsync(counts, 0, (size_t)N * 4, stream);
    hist_kernel<<<(E + 255) / 256, 256, 0, stream>>>(ei, counts, E);
    scan1_kernel<<<NB, 256, 0, stream>>>(counts, offsets, bsum, N);
    scan2_kernel<<<1, 64, 0, stream>>>(bsum, bscan, NB);
    scan3_kernel<<<(N + 1 + 255) / 256, 256, 0, stream>>>(offsets, bscan, N, E);
    hipMemcpyAsync(cursor, offsets, (size_t)N * 4, hipMemcpyDeviceToDevice, stream);
    reorder_kernel<<<(E + 255) / 256, 256, 0, stream>>>(ei, ev, cursor, ecv, E);

    // atomic-free accumulate + identity + bias
    accum_kernel<<<(N + 3) / 4, 256, 0, stream>>>(ecv, offsets, S, bias, out, N);
}